// Round 2
// baseline (422.380 us; speedup 1.0000x reference)
//
#include <hip/hip_runtime.h>
#include <stdint.h>

// DiffAttention fwd: B=2, N=2048, EMB=1024, H=8 heads, 2 sub-heads of HD=64 each.
// Pipeline: cvt(f32->bf16) -> lambda -> fused QKV NT-GEMM (V written transposed)
//           -> flash attention (swapped-MFMA, lane-local softmax) -> out GEMM.

typedef __attribute__((ext_vector_type(8))) __bf16 bf16x8;
typedef __attribute__((ext_vector_type(4))) float f32x4;
typedef __attribute__((ext_vector_type(8))) unsigned short u16x8;
typedef __attribute__((ext_vector_type(4))) unsigned short u16x4;
typedef unsigned short u16;
typedef unsigned int u32;

#define EMB 1024
#define NSEQ 2048
#define NBATCH 2
#define NHEAD 8
#define MROWS (NBATCH*NSEQ)   // 4096

__device__ __forceinline__ u16 f2bf(float f){
  u32 x = __builtin_bit_cast(u32, f);
  return (u16)((x + 0x7fffu + ((x >> 16) & 1u)) >> 16);   // RNE (inputs are finite)
}

__device__ __forceinline__ bf16x8 ld8(const u16* p){
  return __builtin_bit_cast(bf16x8, *(const u16x8*)p);
}

// async global->LDS, 16B per lane; LDS dest = wave-uniform base + lane*16
__device__ __forceinline__ void glds16(const u16* g, u16* l){
  __builtin_amdgcn_global_load_lds(
      (const __attribute__((address_space(1))) u32*)g,
      (__attribute__((address_space(3))) u32*)l, 16, 0, 0);
}

// ---------------- f32 -> bf16 conversion of all operands ----------------
__global__ void cvt_k(const float* __restrict__ q, const float* __restrict__ k,
                      const float* __restrict__ v, const float* __restrict__ Wq,
                      const float* __restrict__ Wk, const float* __restrict__ Wv,
                      const float* __restrict__ Wo,
                      u16* qb, u16* kb, u16* vb, u16* Wqb, u16* Wkb, u16* Wvb, u16* Wob)
{
  const int NQ4 = (NBATCH*NSEQ*EMB)/4;   // 1048576 float4 per q/k/v
  const int NW4 = (EMB*EMB)/4;           // 262144 per W
  const int total = 3*NQ4 + 4*NW4;
  for (int i = blockIdx.x*blockDim.x + threadIdx.x; i < total; i += gridDim.x*blockDim.x){
    const float* src; u16* dst; int off;
    if (i < 3*NQ4){
      int t = i / NQ4; off = i - t*NQ4;
      src = t==0 ? q : (t==1 ? k : v);
      dst = t==0 ? qb : (t==1 ? kb : vb);
    } else {
      int j = i - 3*NQ4;
      int t = j / NW4; off = j - t*NW4;
      src = t==0 ? Wq : (t==1 ? Wk : (t==2 ? Wv : Wo));
      dst = t==0 ? Wqb : (t==1 ? Wkb : (t==2 ? Wvb : Wob));
    }
    f32x4 f = *((const f32x4*)src + off);
    u16x4 u; u[0]=f2bf(f[0]); u[1]=f2bf(f[1]); u[2]=f2bf(f[2]); u[3]=f2bf(f[3]);
    *((u16x4*)dst + off) = u;
  }
}

// ---------------- lambda scalar ----------------
__global__ void lambda_k(const float* __restrict__ lq1, const float* __restrict__ lk1,
                         const float* __restrict__ lq2, const float* __restrict__ lk2,
                         float* lam)
{
  int l = threadIdx.x;                 // 64 threads
  float p1 = lq1[l]*lk1[l];
  float p2 = lq2[l]*lk2[l];
  #pragma unroll
  for (int m=1; m<64; m<<=1){ p1 += __shfl_xor(p1, m, 64); p2 += __shfl_xor(p2, m, 64); }
  if (l==0) lam[0] = __expf(p1) - __expf(p2) + 0.8f;
}

// ---------------- NT GEMM core: Y[m,n] = sum_k A[m,k]*W[n,k] + bias[n] ----------------
__device__ __forceinline__ void gemm_core(
    const u16* __restrict__ A, const u16* __restrict__ W, const float* __restrict__ bias,
    u16* __restrict__ Ybf, u16* __restrict__ Yvt, float* __restrict__ Yf, int mode,
    u16* As, u16* Bs)
{
  const int tid = threadIdx.x, w = tid >> 6, l = tid & 63;
  const int l15 = l & 15, lg = l >> 4;
  const int m0 = blockIdx.y * 128, n0 = blockIdx.x * 128;
  const int wr = w >> 1, wc = w & 1;
  const int srow = w*16 + (l >> 2);    // staging row within a 64-row half
  const int skel = (l & 3) * 8;        // staging k-elem offset (16B)

  f32x4 acc[4][4] = {};

  for (int kt = 0; kt < EMB/32; ++kt){
    const int kb = kt*32 + skel;
    glds16(A + (size_t)(m0 + srow)*EMB + kb,      As + w*512);
    glds16(A + (size_t)(m0 + 64 + srow)*EMB + kb, As + 2048 + w*512);
    glds16(W + (size_t)(n0 + srow)*EMB + kb,      Bs + w*512);
    glds16(W + (size_t)(n0 + 64 + srow)*EMB + kb, Bs + 2048 + w*512);
    __syncthreads();   // drains vmcnt for global_load_lds

    bf16x8 af[4], bfr[4];
    #pragma unroll
    for (int mi=0; mi<4; ++mi) af[mi]  = ld8(As + (wr*64 + mi*16 + l15)*32 + lg*8);
    #pragma unroll
    for (int ni=0; ni<4; ++ni) bfr[ni] = ld8(Bs + (wc*64 + ni*16 + l15)*32 + lg*8);
    #pragma unroll
    for (int mi=0; mi<4; ++mi)
      #pragma unroll
      for (int ni=0; ni<4; ++ni)
        acc[mi][ni] = __builtin_amdgcn_mfma_f32_16x16x32_bf16(af[mi], bfr[ni], acc[mi][ni], 0,0,0);
    __syncthreads();
  }

  #pragma unroll
  for (int mi=0; mi<4; ++mi){
    const int mr = m0 + wr*64 + mi*16 + lg*4;   // + i rows, D: row=(l>>4)*4+i, col=l&15
    #pragma unroll
    for (int ni=0; ni<4; ++ni){
      const int nc = n0 + wc*64 + ni*16 + l15;
      const float bv = bias[nc];
      if (mode == 0){
        #pragma unroll
        for (int i=0;i<4;++i) Ybf[(size_t)(mr+i)*EMB + nc] = f2bf(acc[mi][ni][i] + bv);
      } else if (mode == 1){
        const int h = nc >> 7, vd = nc & 127, bb = mr >> 11, t = mr & 2047;
        u16x4 pk;
        #pragma unroll
        for (int i=0;i<4;++i) pk[i] = f2bf(acc[mi][ni][i] + bv);
        *(u16x4*)(Yvt + ((size_t)((bb*NHEAD + h)*128 + vd))*NSEQ + t) = pk;
      } else {
        #pragma unroll
        for (int i=0;i<4;++i) Yf[(size_t)(mr+i)*EMB + nc] = acc[mi][ni][i] + bv;
      }
    }
  }
}

__global__ __launch_bounds__(256) void gemm_qkv(
    const u16* qb, const u16* kb, const u16* vb,
    const u16* Wqb, const u16* Wkb, const u16* Wvb,
    const float* bq, const float* bk, const float* bv,
    u16* Qp, u16* Kp, u16* Vt)
{
  __shared__ __align__(16) u16 As[4096], Bs[4096];
  const int z = blockIdx.z;
  const u16* A = z==0 ? qb : (z==1 ? kb : vb);
  const u16* W = z==0 ? Wqb : (z==1 ? Wkb : Wvb);
  const float* bias = z==0 ? bq : (z==1 ? bk : bv);
  if (z < 2) gemm_core(A, W, bias, z==0 ? Qp : Kp, nullptr, nullptr, 0, As, Bs);
  else       gemm_core(A, W, bias, nullptr, Vt, nullptr, 1, As, Bs);
}

__global__ __launch_bounds__(256) void gemm_out_k(
    const u16* Xc, const u16* Wob, const float* bo, float* out)
{
  __shared__ __align__(16) u16 As[4096], Bs[4096];
  gemm_core(Xc, Wob, bo, nullptr, nullptr, out, 2, As, Bs);
}

// ---------------- differential flash attention (swapped-MFMA form) ----------------
// grid: 1024 blocks = (b,h) x 64 q-tiles of 32 rows; 4 waves: (pair p = w>>1) x (subhead s = w&1).
// Each wave: 16 q rows, one sub-head, all 2048 keys.
// Swapped QK^T: P^T = mfma(K_frag, Q_frag) -> q = lane&15 lane-local.
// Swapped PV:   O^T = mfma(Vt_frag, Pt_frag) -> q stays lane-local; Vt layout feeds A-frag.
// Diff-combine across the s=0/s=1 wave pair via LDS at the end.
__global__ __launch_bounds__(256, 4) void attn_k(
    const u16* __restrict__ Qp, const u16* __restrict__ Kp,
    const u16* __restrict__ Vt, const float* __restrict__ lamp,
    u16* __restrict__ Xc)
{
  __shared__ __align__(16) char pool[2*16*132*4];   // 16896 B: P pool during loop, Cmb after
  const int tid = threadIdx.x, w = tid >> 6, l = tid & 63;
  const int l15 = l & 15, lg = l >> 4;
  const int bid = blockIdx.x;
  const int qt = bid & 63, bh = bid >> 6;
  const int b = bh >> 3, h = bh & 7;
  const int p = w >> 1, s = w & 1;
  const int q0 = qt*32 + p*16;
  const float C = 0.125f * 1.4426950408889634f;    // scale * log2(e)

  u16* P = (u16*)pool + w*(16*72 + 16);            // per-wave 16x72 bf16, +16 pad

  // Q fragment (B-frag of swapped QK): lane holds Q[q0+l15][d = ks*32+lg*8 ..+7]
  const u16* qbase = Qp + (size_t)(b*NSEQ + q0 + l15)*EMB + (2*h+s)*64;
  bf16x8 qa[2];
  #pragma unroll
  for (int ks=0; ks<2; ++ks) qa[ks] = ld8(qbase + ks*32 + lg*8);

  f32x4 acc[8] = {};            // O^T: acc[vt], row vd=vt*16+lg*4+i, col q=l15
  float m_run = -1e30f, l_run = 0.f;

  const u16* kbase0 = Kp + (size_t)(b*NSEQ)*EMB + (2*h+s)*64;
  const u16* vbase0 = Vt + (size_t)((b*NHEAD + h)*128)*NSEQ;

  for (int kt = 0; kt < NSEQ/64; ++kt){
    const u16* kbase = kbase0 + (size_t)(kt*64)*EMB;
    const u16* vbase = vbase0 + kt*64;

    // QK^T (swapped): st[nt] = P^T tile, row key=nt*16+lg*4+i, col q=l15
    f32x4 st[4] = {};
    #pragma unroll
    for (int nt=0; nt<4; ++nt)
      #pragma unroll
      for (int ks=0; ks<2; ++ks){
        bf16x8 kf = ld8(kbase + (size_t)(nt*16 + l15)*EMB + ks*32 + lg*8);
        st[nt] = __builtin_amdgcn_mfma_f32_16x16x32_bf16(kf, qa[ks], st[nt], 0,0,0);
      }

    // issue V ks=0 fragments early: latency hides under softmax
    bf16x8 vf0[8];
    #pragma unroll
    for (int vt=0; vt<8; ++vt)
      vf0[vt] = ld8(vbase + (size_t)(vt*16 + l15)*NSEQ + lg*8);

    // online softmax — all state lane-local (q = l15)
    float mv0 = fmaxf(fmaxf(st[0][0], st[0][1]), fmaxf(st[0][2], st[0][3]));
    float mv1 = fmaxf(fmaxf(st[1][0], st[1][1]), fmaxf(st[1][2], st[1][3]));
    float mv2 = fmaxf(fmaxf(st[2][0], st[2][1]), fmaxf(st[2][2], st[2][3]));
    float mv3 = fmaxf(fmaxf(st[3][0], st[3][1]), fmaxf(st[3][2], st[3][3]));
    float tm = fmaxf(fmaxf(mv0, mv1), fmaxf(mv2, mv3));
    tm = fmaxf(tm, __shfl_xor(tm, 16, 64));
    tm = fmaxf(tm, __shfl_xor(tm, 32, 64));
    float mn = fmaxf(m_run, tm);
    float al = exp2f((m_run - mn)*C);
    m_run = mn;

    float ssum = 0.f;
    #pragma unroll
    for (int nt=0; nt<4; ++nt){
      #pragma unroll
      for (int i=0;i<4;++i){
        float pv = exp2f((st[nt][i] - mn)*C);
        st[nt][i] = pv; ssum += pv;
      }
    }
    ssum += __shfl_xor(ssum, 16, 64);
    ssum += __shfl_xor(ssum, 32, 64);
    l_run = l_run*al + ssum;

    #pragma unroll
    for (int vt=0; vt<8; ++vt){
      acc[vt][0]*=al; acc[vt][1]*=al; acc[vt][2]*=al; acc[vt][3]*=al;
    }

    // P -> LDS, row-major [q][key], packed b64 writes (2-way bank alias = free)
    #pragma unroll
    for (int nt=0; nt<4; ++nt){
      u16x4 pk;
      pk[0]=f2bf(st[nt][0]); pk[1]=f2bf(st[nt][1]);
      pk[2]=f2bf(st[nt][2]); pk[3]=f2bf(st[nt][3]);
      *(u16x4*)(P + l15*72 + nt*16 + lg*4) = pk;
    }

    // Pt B-frags: lane holds P[q=l15][key = ks*32+lg*8 ..+7]
    bf16x8 pa0 = ld8(P + l15*72 + lg*8);
    bf16x8 pa1 = ld8(P + l15*72 + 32 + lg*8);

    // PV (swapped): acc[vt] += Vt_frag * Pt_frag
    #pragma unroll
    for (int vt=0; vt<8; ++vt)
      acc[vt] = __builtin_amdgcn_mfma_f32_16x16x32_bf16(vf0[vt], pa0, acc[vt], 0,0,0);
    #pragma unroll
    for (int vt=0; vt<8; ++vt){
      bf16x8 vf1 = ld8(vbase + (size_t)(vt*16 + l15)*NSEQ + 32 + lg*8);
      acc[vt] = __builtin_amdgcn_mfma_f32_16x16x32_bf16(vf1, pa1, acc[vt], 0,0,0);
    }
  }

  // diff-combine across the wave pair via LDS (aliases P pool; barrier first)
  const float inv = 1.f / l_run;
  float* Cmb = (float*)pool;            // [2 pairs][16 q][132 pad] f32
  __syncthreads();
  if (s == 1){
    const float f = lamp[0] * inv;
    #pragma unroll
    for (int vt=0; vt<8; ++vt){
      f32x4 vv; vv[0]=acc[vt][0]*f; vv[1]=acc[vt][1]*f; vv[2]=acc[vt][2]*f; vv[3]=acc[vt][3]*f;
      *(f32x4*)(Cmb + (size_t)(p*16 + l15)*132 + vt*16 + lg*4) = vv;
    }
  }
  __syncthreads();
  if (s == 0){
    #pragma unroll
    for (int vt=0; vt<8; ++vt){
      f32x4 c = *(f32x4*)(Cmb + (size_t)(p*16 + l15)*132 + vt*16 + lg*4);
      u16x4 o;
      #pragma unroll
      for (int i=0;i<4;++i) o[i] = f2bf(acc[vt][i]*inv - c[i]);
      *(u16x4*)(Xc + (size_t)(b*NSEQ + q0 + l15)*EMB + h*128 + vt*16 + lg*4) = o;
    }
  }
}

// ---------------- host launch ----------------
extern "C" void kernel_launch(void* const* d_in, const int* in_sizes, int n_in,
                              void* d_out, int out_size, void* d_ws, size_t ws_size,
                              hipStream_t stream)
{
  const float* q   = (const float*)d_in[0];
  const float* k   = (const float*)d_in[1];
  const float* v   = (const float*)d_in[2];
  const float* Wq  = (const float*)d_in[3];
  const float* bq  = (const float*)d_in[4];
  const float* Wk  = (const float*)d_in[5];
  const float* bk  = (const float*)d_in[6];
  const float* Wv  = (const float*)d_in[7];
  const float* bv  = (const float*)d_in[8];
  const float* Wo  = (const float*)d_in[9];
  const float* bo  = (const float*)d_in[10];
  const float* lq1 = (const float*)d_in[11];
  const float* lk1 = (const float*)d_in[12];
  const float* lq2 = (const float*)d_in[13];
  const float* lk2 = (const float*)d_in[14];

  const size_t NQ = (size_t)MROWS*EMB;   // 4194304
  const size_t NW = (size_t)EMB*EMB;     // 1048576
  u16* qb  = (u16*)d_ws;
  u16* kb  = qb + NQ;
  u16* vb  = kb + NQ;
  u16* Wqb = vb + NQ;
  u16* Wkb = Wqb + NW;
  u16* Wvb = Wkb + NW;
  u16* Wob = Wvb + NW;
  u16* Qp  = Wob + NW;
  u16* Kp  = Qp + NQ;
  u16* Vt  = Kp + NQ;
  u16* Xc  = Vt + NQ;
  float* lam = (float*)(Xc + NQ);

  cvt_k<<<2048, 256, 0, stream>>>(q, k, v, Wq, Wk, Wv, Wo,
                                  qb, kb, vb, Wqb, Wkb, Wvb, Wob);
  lambda_k<<<1, 64, 0, stream>>>(lq1, lk1, lq2, lk2, lam);
  gemm_qkv<<<dim3(EMB/128, MROWS/128, 3), 256, 0, stream>>>(
      qb, kb, vb, Wqb, Wkb, Wvb, bq, bk, bv, Qp, Kp, Vt);
  attn_k<<<dim3(NBATCH*NHEAD*(NSEQ/32)), 256, 0, stream>>>(Qp, Kp, Vt, lam, Xc);
  gemm_out_k<<<dim3(EMB/128, MROWS/128), 256, 0, stream>>>(Xc, Wob, bo, (float*)d_out);
}

// Round 3
// 181.755 us; speedup vs baseline: 2.3239x; 2.3239x over previous
//
#include <hip/hip_runtime.h>
#include <stdint.h>

// DiffAttention fwd: B=2, N=2048, EMB=1024, H=8 heads, 2 sub-heads of HD=64 each.
// Pipeline: cvt(f32->bf16) -> lambda -> fused QKV NT-GEMM (V written transposed)
//           -> flash attention (LDS-staged K/V, 2-phase prefetch, swapped-MFMA,
//              lane-local softmax, defer-max) -> out GEMM.

typedef __attribute__((ext_vector_type(8))) __bf16 bf16x8;
typedef __attribute__((ext_vector_type(4))) float f32x4;
typedef __attribute__((ext_vector_type(8))) unsigned short u16x8;
typedef __attribute__((ext_vector_type(4))) unsigned short u16x4;
typedef unsigned short u16;
typedef unsigned int u32;

#define EMB 1024
#define NSEQ 2048
#define NBATCH 2
#define NHEAD 8
#define MROWS (NBATCH*NSEQ)   // 4096

__device__ __forceinline__ u16 f2bf(float f){
  u32 x = __builtin_bit_cast(u32, f);
  return (u16)((x + 0x7fffu + ((x >> 16) & 1u)) >> 16);   // RNE (inputs are finite)
}

__device__ __forceinline__ bf16x8 ld8(const u16* p){
  return __builtin_bit_cast(bf16x8, *(const u16x8*)p);
}

// async global->LDS, 16B per lane; LDS dest = wave-uniform base + lane*16
__device__ __forceinline__ void glds16(const u16* g, u16* l){
  __builtin_amdgcn_global_load_lds(
      (const __attribute__((address_space(1))) u32*)g,
      (__attribute__((address_space(3))) u32*)l, 16, 0, 0);
}

// ---------------- f32 -> bf16 conversion of all operands ----------------
__global__ void cvt_k(const float* __restrict__ q, const float* __restrict__ k,
                      const float* __restrict__ v, const float* __restrict__ Wq,
                      const float* __restrict__ Wk, const float* __restrict__ Wv,
                      const float* __restrict__ Wo,
                      u16* qb, u16* kb, u16* vb, u16* Wqb, u16* Wkb, u16* Wvb, u16* Wob)
{
  const int NQ4 = (NBATCH*NSEQ*EMB)/4;   // 1048576 float4 per q/k/v
  const int NW4 = (EMB*EMB)/4;           // 262144 per W
  const int total = 3*NQ4 + 4*NW4;
  for (int i = blockIdx.x*blockDim.x + threadIdx.x; i < total; i += gridDim.x*blockDim.x){
    const float* src; u16* dst; int off;
    if (i < 3*NQ4){
      int t = i / NQ4; off = i - t*NQ4;
      src = t==0 ? q : (t==1 ? k : v);
      dst = t==0 ? qb : (t==1 ? kb : vb);
    } else {
      int j = i - 3*NQ4;
      int t = j / NW4; off = j - t*NW4;
      src = t==0 ? Wq : (t==1 ? Wk : (t==2 ? Wv : Wo));
      dst = t==0 ? Wqb : (t==1 ? Wkb : (t==2 ? Wvb : Wob));
    }
    f32x4 f = *((const f32x4*)src + off);
    u16x4 u; u[0]=f2bf(f[0]); u[1]=f2bf(f[1]); u[2]=f2bf(f[2]); u[3]=f2bf(f[3]);
    *((u16x4*)dst + off) = u;
  }
}

// ---------------- lambda scalar ----------------
__global__ void lambda_k(const float* __restrict__ lq1, const float* __restrict__ lk1,
                         const float* __restrict__ lq2, const float* __restrict__ lk2,
                         float* lam)
{
  int l = threadIdx.x;                 // 64 threads
  float p1 = lq1[l]*lk1[l];
  float p2 = lq2[l]*lk2[l];
  #pragma unroll
  for (int m=1; m<64; m<<=1){ p1 += __shfl_xor(p1, m, 64); p2 += __shfl_xor(p2, m, 64); }
  if (l==0) lam[0] = __expf(p1) - __expf(p2) + 0.8f;
}

// ---------------- NT GEMM core: Y[m,n] = sum_k A[m,k]*W[n,k] + bias[n] ----------------
__device__ __forceinline__ void gemm_core(
    const u16* __restrict__ A, const u16* __restrict__ W, const float* __restrict__ bias,
    u16* __restrict__ Ybf, u16* __restrict__ Yvt, float* __restrict__ Yf, int mode,
    u16* As, u16* Bs)
{
  const int tid = threadIdx.x, w = tid >> 6, l = tid & 63;
  const int l15 = l & 15, lg = l >> 4;
  const int m0 = blockIdx.y * 128, n0 = blockIdx.x * 128;
  const int wr = w >> 1, wc = w & 1;
  const int srow = w*16 + (l >> 2);    // staging row within a 64-row half
  const int skel = (l & 3) * 8;        // staging k-elem offset (16B)

  f32x4 acc[4][4] = {};

  for (int kt = 0; kt < EMB/32; ++kt){
    const int kb = kt*32 + skel;
    glds16(A + (size_t)(m0 + srow)*EMB + kb,      As + w*512);
    glds16(A + (size_t)(m0 + 64 + srow)*EMB + kb, As + 2048 + w*512);
    glds16(W + (size_t)(n0 + srow)*EMB + kb,      Bs + w*512);
    glds16(W + (size_t)(n0 + 64 + srow)*EMB + kb, Bs + 2048 + w*512);
    __syncthreads();   // drains vmcnt for global_load_lds

    bf16x8 af[4], bfr[4];
    #pragma unroll
    for (int mi=0; mi<4; ++mi) af[mi]  = ld8(As + (wr*64 + mi*16 + l15)*32 + lg*8);
    #pragma unroll
    for (int ni=0; ni<4; ++ni) bfr[ni] = ld8(Bs + (wc*64 + ni*16 + l15)*32 + lg*8);
    #pragma unroll
    for (int mi=0; mi<4; ++mi)
      #pragma unroll
      for (int ni=0; ni<4; ++ni)
        acc[mi][ni] = __builtin_amdgcn_mfma_f32_16x16x32_bf16(af[mi], bfr[ni], acc[mi][ni], 0,0,0);
    __syncthreads();
  }

  #pragma unroll
  for (int mi=0; mi<4; ++mi){
    const int mr = m0 + wr*64 + mi*16 + lg*4;   // + i rows, D: row=(l>>4)*4+i, col=l&15
    #pragma unroll
    for (int ni=0; ni<4; ++ni){
      const int nc = n0 + wc*64 + ni*16 + l15;
      const float bv = bias[nc];
      if (mode == 0){
        #pragma unroll
        for (int i=0;i<4;++i) Ybf[(size_t)(mr+i)*EMB + nc] = f2bf(acc[mi][ni][i] + bv);
      } else if (mode == 1){
        const int h = nc >> 7, vd = nc & 127, bb = mr >> 11, t = mr & 2047;
        u16x4 pk;
        #pragma unroll
        for (int i=0;i<4;++i) pk[i] = f2bf(acc[mi][ni][i] + bv);
        *(u16x4*)(Yvt + ((size_t)((bb*NHEAD + h)*128 + vd))*NSEQ + t) = pk;
      } else {
        #pragma unroll
        for (int i=0;i<4;++i) Yf[(size_t)(mr+i)*EMB + nc] = acc[mi][ni][i] + bv;
      }
    }
  }
}

__global__ __launch_bounds__(256) void gemm_qkv(
    const u16* qb, const u16* kb, const u16* vb,
    const u16* Wqb, const u16* Wkb, const u16* Wvb,
    const float* bq, const float* bk, const float* bv,
    u16* Qp, u16* Kp, u16* Vt)
{
  __shared__ __align__(16) u16 As[4096], Bs[4096];
  const int z = blockIdx.z;
  const u16* A = z==0 ? qb : (z==1 ? kb : vb);
  const u16* W = z==0 ? Wqb : (z==1 ? Wkb : Wvb);
  const float* bias = z==0 ? bq : (z==1 ? bk : bv);
  if (z < 2) gemm_core(A, W, bias, z==0 ? Qp : Kp, nullptr, nullptr, 0, As, Bs);
  else       gemm_core(A, W, bias, nullptr, Vt, nullptr, 1, As, Bs);
}

__global__ __launch_bounds__(256) void gemm_out_k(
    const u16* Xc, const u16* Wob, const float* bo, float* out)
{
  __shared__ __align__(16) u16 As[4096], Bs[4096];
  gemm_core(Xc, Wob, bo, nullptr, nullptr, out, 2, As, Bs);
}

// ---------------- differential flash attention v3 ----------------
// grid: 512 blocks = (b,h) x 32 q-tiles of 64 rows; 4 waves, each owns 16 q rows,
// BOTH sub-heads. K/V tiles staged in LDS (coalesced glds, XOR-swizzled via
// pre-swizzled global source), shared by all waves; 2-phase prefetch pipeline.
// Swapped MFMA keeps softmax state lane-local (q = lane&15).
__global__ __launch_bounds__(256, 2) void attn_k(
    const u16* __restrict__ Qp, const u16* __restrict__ Kp,
    const u16* __restrict__ Vt, const float* __restrict__ lamp,
    u16* __restrict__ Xc)
{
  __shared__ __align__(16) u16 ldsK[2*64*128];   // 32KB: K tile [64 key][128 d], dbuf
  __shared__ __align__(16) u16 ldsV[2*128*64];   // 32KB: V^T tile [128 vd][64 t], dbuf
  __shared__ __align__(16) u16 ldsP[4*2*16*64];  // 16KB: per-wave P [s][16 q][64 key]

  const int tid = threadIdx.x, w = tid >> 6, l = tid & 63;
  const int l15 = l & 15, lg = l >> 4, rx = l15 & 7;
  int bid = blockIdx.x;
  bid = (bid & 7)*64 + (bid >> 3);     // XCD chunk swizzle (512 = 8 XCD x 64)
  const int qt = bid & 31, bh = bid >> 5;
  const int b = bh >> 3, h = bh & 7;
  const int q0 = qt*64 + w*16;
  const float C = 0.125f * 1.4426950408889634f;  // scale * log2(e)
  const float lam = lamp[0];

  const u16* Kg = Kp + ((size_t)b*NSEQ)*EMB + h*128;          // both sub-heads: 128 dims
  const u16* Vg = Vt + ((size_t)((b*NHEAD + h)*128))*NSEQ;

  // Q fragments (B-frag of swapped QK): lane holds Q[q0+l15][d = ks*32+lg*8 ..+7]
  const u16* qbase = Qp + (size_t)(b*NSEQ + q0 + l15)*EMB + 2*h*64;
  bf16x8 qa[2][2];
  #pragma unroll
  for (int s2=0; s2<2; ++s2)
    #pragma unroll
    for (int ks=0; ks<2; ++ks)
      qa[s2][ks] = ld8(qbase + s2*64 + ks*32 + lg*8);

  f32x4 acc[2][8] = {};                // O^T per s: row vd=vt*16+lg*4+i, col q=l15
  float m_run[2] = {-1e30f, -1e30f}, l_run[2] = {0.f, 0.f};

  u16* Pw = ldsP + w*2048;

  const int srK = l >> 4, ssK = l & 15;   // K staging: 4 rows x 16 chunks per glds
  const int srV = l >> 3, ssV = l & 7;    // V staging: 8 rows x 8 chunks per glds

  auto STAGE = [&](int cur, int kt){
    const u16* kg = Kg + ((size_t)kt*64)*EMB;
    u16* kd = ldsK + cur*8192;
    #pragma unroll
    for (int j=0;j<4;++j){
      int row = w*16 + j*4 + srK;
      glds16(kg + (size_t)row*EMB + ((ssK ^ (row&7))*8), kd + (w*16 + j*4)*128);
    }
    const u16* vg = Vg + kt*64;
    u16* vd2 = ldsV + cur*8192;
    #pragma unroll
    for (int j=0;j<4;++j){
      int row = w*32 + j*8 + srV;
      glds16(vg + (size_t)row*NSEQ + ((ssV ^ (row&7))*8), vd2 + (w*32 + j*8)*64);
    }
  };

  STAGE(0, 0);
  __syncthreads();
  int cur = 0;

  for (int kt = 0; kt < NSEQ/64; ++kt){
    if (kt+1 < NSEQ/64) STAGE(cur^1, kt+1);   // prefetch: drains at this iter's barrier

    const u16* Kb = ldsK + cur*8192;
    const u16* Vb = ldsV + cur*8192;

    // QK^T (swapped): st[s][nt] rows key=nt*16+lg*4+i, col q=l15
    f32x4 st[2][4] = {};
    #pragma unroll
    for (int s2=0; s2<2; ++s2)
      #pragma unroll
      for (int nt=0; nt<4; ++nt)
        #pragma unroll
        for (int ks=0; ks<2; ++ks){
          bf16x8 kf = ld8(Kb + (nt*16 + l15)*128 + (((s2*8 + ks*4 + lg) ^ rx)*8));
          st[s2][nt] = __builtin_amdgcn_mfma_f32_16x16x32_bf16(kf, qa[s2][ks], st[s2][nt], 0,0,0);
        }

    // per-sub-head online softmax (lane-local, defer-max) + P write
    #pragma unroll
    for (int s2=0; s2<2; ++s2){
      float tm = fmaxf(fmaxf(st[s2][0][0], st[s2][0][1]), fmaxf(st[s2][0][2], st[s2][0][3]));
      #pragma unroll
      for (int nt=1; nt<4; ++nt)
        tm = fmaxf(tm, fmaxf(fmaxf(st[s2][nt][0], st[s2][nt][1]),
                             fmaxf(st[s2][nt][2], st[s2][nt][3])));
      tm = fmaxf(tm, __shfl_xor(tm, 16, 64));
      tm = fmaxf(tm, __shfl_xor(tm, 32, 64));
      if (!__all(tm <= m_run[s2] + 8.f)){     // T13 defer-max: P bounded by 2^1.45
        float mn = fmaxf(m_run[s2], tm);
        float al = exp2f((m_run[s2] - mn)*C);
        m_run[s2] = mn;
        l_run[s2] *= al;
        #pragma unroll
        for (int vt=0; vt<8; ++vt){
          acc[s2][vt][0]*=al; acc[s2][vt][1]*=al; acc[s2][vt][2]*=al; acc[s2][vt][3]*=al;
        }
      }
      float ssum = 0.f;
      #pragma unroll
      for (int nt=0; nt<4; ++nt)
        #pragma unroll
        for (int i=0;i<4;++i){
          float pv = exp2f((st[s2][nt][i] - m_run[s2])*C);
          st[s2][nt][i] = pv; ssum += pv;
        }
      ssum += __shfl_xor(ssum, 16, 64);
      ssum += __shfl_xor(ssum, 32, 64);
      l_run[s2] += ssum;

      // P -> LDS [16 q][64 key], swizzled (chunk ^= q&7); row=128B, u16x4 writes
      #pragma unroll
      for (int nt=0; nt<4; ++nt){
        u16x4 pk;
        pk[0]=f2bf(st[s2][nt][0]); pk[1]=f2bf(st[s2][nt][1]);
        pk[2]=f2bf(st[s2][nt][2]); pk[3]=f2bf(st[s2][nt][3]);
        int chunk = 2*nt + (lg>>1);
        *(u16x4*)(Pw + s2*1024 + l15*64 + ((chunk^rx)*8) + (lg&1)*4) = pk;
      }
    }

    // P^T B-frags: lane holds P[q=l15][key = ks*32+lg*8 ..+7]
    bf16x8 pa[2][2];
    #pragma unroll
    for (int s2=0; s2<2; ++s2)
      #pragma unroll
      for (int ks=0; ks<2; ++ks)
        pa[s2][ks] = ld8(Pw + s2*1024 + l15*64 + (((ks*4 + lg)^rx)*8));

    // PV (swapped): V frag read once, feeds both sub-heads
    #pragma unroll
    for (int ks=0; ks<2; ++ks)
      #pragma unroll
      for (int vt=0; vt<8; ++vt){
        bf16x8 vf = ld8(Vb + (vt*16 + l15)*64 + (((ks*4 + lg)^rx)*8));
        acc[0][vt] = __builtin_amdgcn_mfma_f32_16x16x32_bf16(vf, pa[0][ks], acc[0][vt], 0,0,0);
        acc[1][vt] = __builtin_amdgcn_mfma_f32_16x16x32_bf16(vf, pa[1][ks], acc[1][vt], 0,0,0);
      }

    __syncthreads();    // drains prefetch vmcnt + LDS reads before buffer swap
    cur ^= 1;
  }

  // epilogue: diff-combine in-register
  const float i0 = 1.f / l_run[0];
  const float i1 = lam / l_run[1];
  #pragma unroll
  for (int vt=0; vt<8; ++vt){
    u16x4 o;
    #pragma unroll
    for (int i=0;i<4;++i) o[i] = f2bf(acc[0][vt][i]*i0 - acc[1][vt][i]*i1);
    *(u16x4*)(Xc + (size_t)(b*NSEQ + q0 + l15)*EMB + h*128 + vt*16 + lg*4) = o;
  }
}

// ---------------- host launch ----------------
extern "C" void kernel_launch(void* const* d_in, const int* in_sizes, int n_in,
                              void* d_out, int out_size, void* d_ws, size_t ws_size,
                              hipStream_t stream)
{
  const float* q   = (const float*)d_in[0];
  const float* k   = (const float*)d_in[1];
  const float* v   = (const float*)d_in[2];
  const float* Wq  = (const float*)d_in[3];
  const float* bq  = (const float*)d_in[4];
  const float* Wk  = (const float*)d_in[5];
  const float* bk  = (const float*)d_in[6];
  const float* Wv  = (const float*)d_in[7];
  const float* bv  = (const float*)d_in[8];
  const float* Wo  = (const float*)d_in[9];
  const float* bo  = (const float*)d_in[10];
  const float* lq1 = (const float*)d_in[11];
  const float* lk1 = (const float*)d_in[12];
  const float* lq2 = (const float*)d_in[13];
  const float* lk2 = (const float*)d_in[14];

  const size_t NQ = (size_t)MROWS*EMB;   // 4194304
  const size_t NW = (size_t)EMB*EMB;     // 1048576
  u16* qb  = (u16*)d_ws;
  u16* kb  = qb + NQ;
  u16* vb  = kb + NQ;
  u16* Wqb = vb + NQ;
  u16* Wkb = Wqb + NW;
  u16* Wvb = Wkb + NW;
  u16* Wob = Wvb + NW;
  u16* Qp  = Wob + NW;
  u16* Kp  = Qp + NQ;
  u16* Vt  = Kp + NQ;
  u16* Xc  = Vt + NQ;
  float* lam = (float*)(Xc + NQ);

  cvt_k<<<2048, 256, 0, stream>>>(q, k, v, Wq, Wk, Wv, Wo,
                                  qb, kb, vb, Wqb, Wkb, Wvb, Wob);
  lambda_k<<<1, 64, 0, stream>>>(lq1, lk1, lq2, lk2, lam);
  gemm_qkv<<<dim3(EMB/128, MROWS/128, 3), 256, 0, stream>>>(
      qb, kb, vb, Wqb, Wkb, Wvb, bq, bk, bv, Qp, Kp, Vt);
  attn_k<<<dim3(NBATCH*NHEAD*(NSEQ/64)), 256, 0, stream>>>(Qp, Kp, Vt, lam, Xc);
  gemm_out_k<<<dim3(EMB/128, MROWS/128), 256, 0, stream>>>(Xc, Wob, bo, (float*)d_out);
}